// Round 12
// baseline (183.838 us; speedup 1.0000x reference)
//
#include <hip/hip_runtime.h>
#include <hip/hip_bf16.h>
#include <math.h>

#define D_MODEL 512
#define N_HEADS 8
#define D_K     64
#define T_SEQ   2048
#define B_SZ    4
#define M_ROWS  (B_SZ * T_SEQ)   // 8192

typedef __bf16 bf16;
typedef __bf16 bf16x4 __attribute__((ext_vector_type(4)));
typedef __bf16 bf16x8 __attribute__((ext_vector_type(8)));
typedef float  floatx4 __attribute__((ext_vector_type(4)));

// 16B-atom XOR swizzle for stride-64 bf16 LDS tiles: conflict-free b128
// fragment access (padding cannot fix b128 tiles: stride%4dw==0 -> 8-way).
__device__ __forceinline__ int SWZ(int row, int col) {
  return row * 64 + ((((col >> 3) ^ (row & 7)) << 3) | (col & 7));
}

// ---------------------------------------------------------------------------
// Sinusoidal PE value for (t, d), d in [0,64) — fast intrinsics.
// ---------------------------------------------------------------------------
__device__ __forceinline__ float pe_fast(int t, int d) {
  int i2 = d & ~1;
  float div = __expf((float)i2 * (-0.1439115683f));  // -ln(10000)/64
  float ang = (float)t * div;
  return (d & 1) ? __cosf(ang) : __sinf(ang);
}

// ---------------------------------------------------------------------------
// prep v3: one-wave-per-row LayerNorm (blocks 0..2047, 4 rows/block) +
// weight f32->bf16 convert (blocks 2048..3071; now ONE bf16x4 store
// instead of 4 scalar 2B stores). No LDS, no barriers.
// ---------------------------------------------------------------------------
__global__ __launch_bounds__(256) void prep(
    const float* __restrict__ x, const float* __restrict__ g,
    const float* __restrict__ b, bf16* __restrict__ out,
    const float* __restrict__ wq, const float* __restrict__ wk,
    const float* __restrict__ wv, const float* __restrict__ wo,
    bf16* __restrict__ wdst) {
  int bid = blockIdx.x;
  int tid = threadIdx.x;
  if (bid >= M_ROWS / 4) {
    int gid = (bid - M_ROWS / 4) * 256 + tid;
    int e0  = gid * 4;
    int mat = e0 >> 18;
    int loc = e0 & 262143;
    const float* src = (mat == 0) ? wq : (mat == 1) ? wk : (mat == 2) ? wv : wo;
    float4 v = *(const float4*)(src + loc);
    bf16x4 pk;
    pk[0] = (bf16)v.x; pk[1] = (bf16)v.y; pk[2] = (bf16)v.z; pk[3] = (bf16)v.w;
    *(bf16x4*)(wdst + e0) = pk;
    return;
  }
  int wave = tid >> 6, lane = tid & 63;
  int row  = bid * 4 + wave;
  const float* xr = x + (size_t)row * D_MODEL + lane * 8;
  float4 a = *(const float4*)(xr);
  float4 c = *(const float4*)(xr + 4);
  float s  = a.x + a.y + a.z + a.w + c.x + c.y + c.z + c.w;
  float ss = a.x * a.x + a.y * a.y + a.z * a.z + a.w * a.w +
             c.x * c.x + c.y * c.y + c.z * c.z + c.w * c.w;
#pragma unroll
  for (int off = 1; off < 64; off <<= 1) {
    s  += __shfl_xor(s,  off, 64);
    ss += __shfl_xor(ss, off, 64);
  }
  float mu  = s * (1.0f / D_MODEL);
  float var = ss * (1.0f / D_MODEL) - mu * mu;
  float rs  = rsqrtf(var + 1e-5f);
  float4 g0 = *(const float4*)(g + lane * 8);
  float4 g1 = *(const float4*)(g + lane * 8 + 4);
  float4 b0 = *(const float4*)(b + lane * 8);
  float4 b1 = *(const float4*)(b + lane * 8 + 4);
  bf16x8 o8;
  o8[0] = (bf16)((a.x - mu) * rs * g0.x + b0.x);
  o8[1] = (bf16)((a.y - mu) * rs * g0.y + b0.y);
  o8[2] = (bf16)((a.z - mu) * rs * g0.z + b0.z);
  o8[3] = (bf16)((a.w - mu) * rs * g0.w + b0.w);
  o8[4] = (bf16)((c.x - mu) * rs * g1.x + b1.x);
  o8[5] = (bf16)((c.y - mu) * rs * g1.y + b1.y);
  o8[6] = (bf16)((c.z - mu) * rs * g1.z + b1.z);
  o8[7] = (bf16)((c.w - mu) * rs * g1.w + b1.w);
  *(bf16x8*)(out + (size_t)row * D_MODEL + lane * 8) = o8;
}

// ---------------------------------------------------------------------------
// QKV projection v9 — K-SPLIT + ISSUE-EARLY A-loads.
// R11 theory: per phase the af global loads were issued after the staging
// barrier with the MFMA burst depending on them -> ~500-800 cyc exposed
// latency/phase at 3 waves/SIMD. af touches no LDS, so issue it BEFORE the
// read-done barrier + staging ds_writes (T14 issue-early): latency hides
// under barrier wait + staging.
// ---------------------------------------------------------------------------
__global__ __launch_bounds__(256, 3) void gemm_qkv(
    const bf16* __restrict__ A, const bf16* __restrict__ wqkv,
    const float* __restrict__ bq, const float* __restrict__ bk, const float* __restrict__ bv,
    bf16* __restrict__ Qo, bf16* __restrict__ Ko, bf16* __restrict__ VTo) {
  __shared__ bf16 sW[16384];             // 4 tiles of [64n][64k] = 32 KB
  __shared__ bf16 ep[4][1536];           // per-wave epilogue chunks (12 KB)

  int tid = threadIdx.x;
  int w = tid >> 6, lane = tid & 63;
  int lm = lane & 15, quad = lane >> 4;
  int mat  = blockIdx.y >> 3;            // 0=Q,1=K,2=V
  int h    = blockIdx.y & 7;
  int nloc = h * 64;
  const bf16* Wp = wqkv + (size_t)mat * 262144;

  int mbase = blockIdx.x * 128 + w * 32;
  const bf16* ap = A + (size_t)(mbase + lm) * D_MODEL + quad * 8;

  floatx4 acc[2][4];
#pragma unroll
  for (int mi = 0; mi < 2; mi++)
#pragma unroll
    for (int nt = 0; nt < 4; nt++) acc[mi][nt] = floatx4{0.f, 0.f, 0.f, 0.f};

  int srow = tid >> 2;
  int scc  = (tid & 3) * 16;

#pragma unroll 1
  for (int kp = 0; kp < 2; kp++) {
    // ---- issue A-loads FIRST (no LDS dependence): latency hides under
    //      the barrier + staging below ----
    bf16x8 af[2][8];
#pragma unroll
    for (int mi = 0; mi < 2; mi++)
#pragma unroll
      for (int ks = 0; ks < 8; ks++)
        af[mi][ks] = *(const bf16x8*)(ap + mi * 16 * D_MODEL + kp * 256 + ks * 32);

    if (kp) __syncthreads();             // all reads of phase-0 sW done
#pragma unroll
    for (int kc = 0; kc < 4; kc++) {
      const bf16* src = Wp + (size_t)(nloc + srow) * D_MODEL + kp * 256 + kc * 64 + scc;
      bf16x8 w0 = *(const bf16x8*)src;
      bf16x8 w1 = *(const bf16x8*)(src + 8);
      *(bf16x8*)&sW[kc * 4096 + SWZ(srow, scc)]     = w0;
      *(bf16x8*)&sW[kc * 4096 + SWZ(srow, scc + 8)] = w1;
    }
    __syncthreads();

#pragma unroll
    for (int ks = 0; ks < 8; ks++) {
#pragma unroll
      for (int nt = 0; nt < 4; nt++) {
        bf16x8 bfr = *(const bf16x8*)
            &sW[(ks >> 1) * 4096 + SWZ(nt * 16 + lm, (ks & 1) * 32 + quad * 8)];
        acc[0][nt] = __builtin_amdgcn_mfma_f32_16x16x32_bf16(af[0][ks], bfr, acc[0][nt], 0, 0, 0);
        acc[1][nt] = __builtin_amdgcn_mfma_f32_16x16x32_bf16(af[1][ks], bfr, acc[1][nt], 0, 0, 0);
      }
    }
  }

  // ---- epilogue (wave-private ep chunks) ----
  int bb = mbase >> 11, t0w = mbase & (T_SEQ - 1);
  size_t bhoff = (size_t)(bb * N_HEADS + h) * (T_SEQ * D_K);
  bf16* myep = ep[w];

  if (mat == 2) {
#pragma unroll
    for (int nt = 0; nt < 4; nt++) {
      float bvv = bv[nloc + nt * 16 + lm];
#pragma unroll
      for (int mi = 0; mi < 2; mi++) {
        bf16x4 pk;
#pragma unroll
        for (int rr = 0; rr < 4; rr++) pk[rr] = (bf16)(acc[mi][nt][rr] + bvv);
        *(bf16x4*)&myep[lm * 40 + mi * 16 + quad * 4] = pk;
      }
      int dl = lane >> 2, toff = (lane & 3) * 8;
      bf16x8 v = *(const bf16x8*)&myep[dl * 40 + toff];
      *(bf16x8*)(VTo + bhoff + (size_t)(nt * 16 + dl) * T_SEQ + t0w + toff) = v;
    }
  } else {
    bf16* dst = (mat == 0) ? Qo : Ko;
    const float* bias = (mat == 0) ? bq : bk;
#pragma unroll
    for (int c = 0; c < 2; c++) {
#pragma unroll
      for (int nt = 0; nt < 4; nt++) {
        int d = nt * 16 + lm;
        float bval = bias[nloc + d];
#pragma unroll
        for (int rr = 0; rr < 4; rr++) {
          float v = acc[c][nt][rr] + bval;
          if (mat == 1) v += pe_fast(t0w + c * 16 + quad * 4 + rr, d);
          else          v *= 0.125f;   // fold 1/sqrt(dk) into Q
          myep[(quad * 4 + rr) * 72 + d] = (bf16)v;
        }
      }
#pragma unroll
      for (int rd = 0; rd < 2; rd++) {
        int row = rd * 8 + (lane >> 3);
        bf16x8 v = *(const bf16x8*)&myep[row * 72 + (lane & 7) * 8];
        *(bf16x8*)(dst + bhoff + (size_t)(t0w + c * 16 + row) * D_K + (lane & 7) * 8) = v;
      }
    }
  }
}

// ---------------------------------------------------------------------------
// Output projection v6 — K-SPLIT + issue-early A-loads (same reorder).
// ---------------------------------------------------------------------------
__global__ __launch_bounds__(256, 3) void gemm_out(const bf16* __restrict__ A,
                                                   const bf16* __restrict__ W,
                                                   const float* __restrict__ bias,
                                                   float* __restrict__ out) {
  __shared__ bf16 sW[16384];             // 4 tiles of [64n][64k] = 32 KB
  int tid = threadIdx.x;
  int w = tid >> 6, lane = tid & 63;
  int lm = lane & 15, quad = lane >> 4;
  int n0 = blockIdx.y * 64;

  int mbase = blockIdx.x * 128 + w * 32;
  const bf16* ap = A + (size_t)(mbase + lm) * D_MODEL + quad * 8;

  floatx4 acc[2][4];
#pragma unroll
  for (int mi = 0; mi < 2; mi++)
#pragma unroll
    for (int nt = 0; nt < 4; nt++) acc[mi][nt] = floatx4{0.f, 0.f, 0.f, 0.f};

  int srow = tid >> 2;
  int scc  = (tid & 3) * 16;

#pragma unroll 1
  for (int kp = 0; kp < 2; kp++) {
    bf16x8 af[2][8];
#pragma unroll
    for (int mi = 0; mi < 2; mi++)
#pragma unroll
      for (int ks = 0; ks < 8; ks++)
        af[mi][ks] = *(const bf16x8*)(ap + mi * 16 * D_MODEL + kp * 256 + ks * 32);

    if (kp) __syncthreads();
#pragma unroll
    for (int kc = 0; kc < 4; kc++) {
      const bf16* src = W + (size_t)(n0 + srow) * D_MODEL + kp * 256 + kc * 64 + scc;
      bf16x8 w0 = *(const bf16x8*)src;
      bf16x8 w1 = *(const bf16x8*)(src + 8);
      *(bf16x8*)&sW[kc * 4096 + SWZ(srow, scc)]     = w0;
      *(bf16x8*)&sW[kc * 4096 + SWZ(srow, scc + 8)] = w1;
    }
    __syncthreads();

#pragma unroll
    for (int ks = 0; ks < 8; ks++) {
#pragma unroll
      for (int nt = 0; nt < 4; nt++) {
        bf16x8 bfr = *(const bf16x8*)
            &sW[(ks >> 1) * 4096 + SWZ(nt * 16 + lm, (ks & 1) * 32 + quad * 8)];
        acc[0][nt] = __builtin_amdgcn_mfma_f32_16x16x32_bf16(af[0][ks], bfr, acc[0][nt], 0, 0, 0);
        acc[1][nt] = __builtin_amdgcn_mfma_f32_16x16x32_bf16(af[1][ks], bfr, acc[1][nt], 0, 0, 0);
      }
    }
  }

#pragma unroll
  for (int nt = 0; nt < 4; nt++) {
    int n = n0 + nt * 16 + lm;
    float bval = bias[n];
#pragma unroll
    for (int mi = 0; mi < 2; mi++)
#pragma unroll
      for (int rr = 0; rr < 4; rr++) {
        int m = mbase + mi * 16 + quad * 4 + rr;
        out[(size_t)m * D_MODEL + n] = acc[mi][nt][rr] + bval;
      }
  }
}

// ---------------------------------------------------------------------------
// MFMA flash attention v6 (reverted from v10) — kg-split, fused per-nt
// softmax, ds_write staging in a dedicated phase. R11 post-mortem: grid =
// 512 blocks = 2/CU exactly, so the sP-shrink could not raise occupancy;
// SWZ32 added 5.2M bank conflicts (+1.2us). v6 = proven 59.0-59.2us.
// ---------------------------------------------------------------------------
__global__ __launch_bounds__(512, 4) void flash_mfma(const bf16* __restrict__ Q,
                                                     const bf16* __restrict__ K,
                                                     const bf16* __restrict__ VT,
                                                     bf16* __restrict__ ctx) {
  __shared__ __align__(16) char smem[65536];
  bf16* sK  = (bf16*)smem;              // [2][64*64] 16 KB, swizzled
  bf16* sVT = (bf16*)(smem + 16384);    // [2][64*64] 16 KB, swizzled
  bf16* sP  = (bf16*)(smem + 32768);    // [8][32*64] 32 KB, swizzled

  int tid  = threadIdx.x;
  int wave = tid >> 6, lane = tid & 63;
  int lm = lane & 15, quad = lane >> 4;
  int qg = wave & 3, kg = wave >> 2;
  int bh = blockIdx.y;
  int q0 = blockIdx.x * 128 + qg * 32;

  const bf16* Qb  = Q  + (size_t)bh * T_SEQ * D_K;
  const bf16* Kb  = K  + (size_t)bh * T_SEQ * D_K;
  const bf16* VTb = VT + (size_t)bh * T_SEQ * D_K;  // [d][t]

  bf16x8 qf[2][2];
#pragma unroll
  for (int qt = 0; qt < 2; qt++)
#pragma unroll
    for (int kb = 0; kb < 2; kb++)
      qf[qt][kb] = *(const bf16x8*)(Qb + (size_t)(q0 + qt * 16 + lm) * D_K + kb * 32 + quad * 8);

  floatx4 o[2][4];
#pragma unroll
  for (int qt = 0; qt < 2; qt++)
#pragma unroll
    for (int nt = 0; nt < 4; nt++) o[qt][nt] = floatx4{0.f, 0.f, 0.f, 0.f};
  float l_i[2] = {0.f, 0.f};

  // staging: 512 threads x (1 b128 per tile per array); 2 tiles per round
  int srow = tid >> 3;
  int scol = (tid & 7) * 8;
  const bf16* kp0 = Kb  + (size_t)srow * D_K + scol;
  const bf16* vp0 = VTb + (size_t)srow * T_SEQ + scol;

  bf16x8 rk[2], rv[2];
  rk[0] = *(const bf16x8*)(kp0);
  rk[1] = *(const bf16x8*)(kp0 + 4096);
  rv[0] = *(const bf16x8*)(vp0);
  rv[1] = *(const bf16x8*)(vp0 + 64);

  bf16* myK = sK  + kg * 4096;
  bf16* myV = sVT + kg * 4096;
  bf16* myP = sP  + wave * 2048;

  for (int r = 0; r < T_SEQ / 64; r += 2) {
    __syncthreads();
    *(bf16x8*)&sK [SWZ(srow, scol)]         = rk[0];
    *(bf16x8*)&sK [4096 + SWZ(srow, scol)]  = rk[1];
    *(bf16x8*)&sVT[SWZ(srow, scol)]         = rv[0];
    *(bf16x8*)&sVT[4096 + SWZ(srow, scol)]  = rv[1];
    if (r + 2 < T_SEQ / 64) {
      rk[0] = *(const bf16x8*)(kp0 + (r + 2) * 4096);
      rk[1] = *(const bf16x8*)(kp0 + (r + 3) * 4096);
      rv[0] = *(const bf16x8*)(vp0 + (r + 2) * 64);
      rv[1] = *(const bf16x8*)(vp0 + (r + 3) * 64);
    }
    __syncthreads();

    // ---- this wave computes tile (r + kg): QK^T fused with softmax per nt ----
    float ls0 = 0.f, ls1 = 0.f;
#pragma unroll
    for (int nt = 0; nt < 4; nt++) {
      floatx4 s0 = floatx4{0.f, 0.f, 0.f, 0.f};
      floatx4 s1 = floatx4{0.f, 0.f, 0.f, 0.f};
#pragma unroll
      for (int kb = 0; kb < 2; kb++) {
        bf16x8 kf = *(const bf16x8*)&myK[SWZ(nt * 16 + lm, kb * 32 + quad * 8)];
        s0 = __builtin_amdgcn_mfma_f32_16x16x32_bf16(kf, qf[0][kb], s0, 0, 0, 0);
        s1 = __builtin_amdgcn_mfma_f32_16x16x32_bf16(kf, qf[1][kb], s1, 0, 0, 0);
      }
      bf16x4 pk0, pk1;
#pragma unroll
      for (int rr = 0; rr < 4; rr++) {
        float p0 = __expf(s0[rr] - 8.0f);
        float p1 = __expf(s1[rr] - 8.0f);
        ls0 += p0; ls1 += p1;
        pk0[rr] = (bf16)p0; pk1[rr] = (bf16)p1;
      }
      *(bf16x4*)&myP[SWZ(lm,      nt * 16 + quad * 4)] = pk0;
      *(bf16x4*)&myP[SWZ(16 + lm, nt * 16 + quad * 4)] = pk1;
    }
    ls0 += __shfl_xor(ls0, 16, 64);
    ls0 += __shfl_xor(ls0, 32, 64);
    ls1 += __shfl_xor(ls1, 16, 64);
    ls1 += __shfl_xor(ls1, 32, 64);
    l_i[0] += ls0;
    l_i[1] += ls1;

#pragma unroll
    for (int kb = 0; kb < 2; kb++) {
      bf16x8 pf0 = *(const bf16x8*)&myP[SWZ(lm, kb * 32 + quad * 8)];
      bf16x8 pf1 = *(const bf16x8*)&myP[SWZ(16 + lm, kb * 32 + quad * 8)];
#pragma unroll
      for (int nt = 0; nt < 4; nt++) {
        bf16x8 vt = *(const bf16x8*)&myV[SWZ(nt * 16 + lm, kb * 32 + quad * 8)];
        o[0][nt] = __builtin_amdgcn_mfma_f32_16x16x32_bf16(pf0, vt, o[0][nt], 0, 0, 0);
        o[1][nt] = __builtin_amdgcn_mfma_f32_16x16x32_bf16(pf1, vt, o[1][nt], 0, 0, 0);
      }
    }
  }

  // ---- merge the two k-group partials (once) ----
  __syncthreads();
  float* scO = (float*)smem;             // [4 qg][8][64 lanes] float4 = 32 KB
  float* scL = (float*)(smem + 32768);   // [4 qg][2][64] = 2 KB
  if (kg == 1) {
#pragma unroll
    for (int qt = 0; qt < 2; qt++)
#pragma unroll
      for (int nt = 0; nt < 4; nt++)
        *(floatx4*)&scO[(qg * 512 + (qt * 4 + nt) * 64 + lane) * 4] = o[qt][nt];
    scL[qg * 128 + lane]      = l_i[0];
    scL[qg * 128 + 64 + lane] = l_i[1];
  }
  __syncthreads();
  if (kg == 0) {
#pragma unroll
    for (int qt = 0; qt < 2; qt++)
#pragma unroll
      for (int nt = 0; nt < 4; nt++) {
        floatx4 t = *(const floatx4*)&scO[(qg * 512 + (qt * 4 + nt) * 64 + lane) * 4];
        o[qt][nt] += t;
      }
    l_i[0] += scL[qg * 128 + lane];
    l_i[1] += scL[qg * 128 + 64 + lane];

    int b_ = bh >> 3, h = bh & 7;
#pragma unroll
    for (int qt = 0; qt < 2; qt++) {
#pragma unroll
      for (int rr = 0; rr < 4; rr++) {
        int qq = quad * 4 + rr;
        float linv = 1.f / __shfl(l_i[qt], qq, 64);
        int t = q0 + qt * 16 + qq;
        bf16* op = ctx + ((size_t)(b_ * T_SEQ + t)) * D_MODEL + h * D_K;
#pragma unroll
        for (int nt = 0; nt < 4; nt++)
          op[nt * 16 + lm] = (bf16)(o[qt][nt][rr] * linv);
      }
    }
  }
}

// ---------------------------------------------------------------------------
extern "C" void kernel_launch(void* const* d_in, const int* in_sizes, int n_in,
                              void* d_out, int out_size, void* d_ws, size_t ws_size,
                              hipStream_t stream) {
  const float* x    = (const float*)d_in[0];
  const float* ln_g = (const float*)d_in[1];
  const float* ln_b = (const float*)d_in[2];
  const float* wq   = (const float*)d_in[3];
  const float* bq   = (const float*)d_in[4];
  const float* wk   = (const float*)d_in[5];
  const float* bk   = (const float*)d_in[6];
  const float* wv   = (const float*)d_in[7];
  const float* bv   = (const float*)d_in[8];
  const float* wo   = (const float*)d_in[9];
  const float* bo   = (const float*)d_in[10];
  float* out = (float*)d_out;

  char* ws = (char*)d_ws;
  const size_t MB8 = (size_t)M_ROWS * D_MODEL * sizeof(bf16);  // 8 MB
  bf16* normed = (bf16*)(ws);                    // dead after gemm_qkv
  bf16* Qb     = (bf16*)(ws + MB8);
  bf16* Kb     = (bf16*)(ws + 2 * MB8);
  bf16* VTb    = (bf16*)(ws + 3 * MB8);          // V^T: [bh][d][t]
  bf16* w4     = (bf16*)(ws + 4 * MB8);          // 2 MB: wq|wk|wv|wo bf16
  bf16* ctx    = normed;                         // alias; ws total 34 MB

  prep<<<M_ROWS / 4 + 1024, 256, 0, stream>>>(x, ln_g, ln_b, normed,
                                              wq, wk, wv, wo, w4);
  gemm_qkv<<<dim3(64, 24), 256, 0, stream>>>(
      normed, w4, bq, bk, bv, Qb, Kb, VTb);
  flash_mfma<<<dim3(T_SEQ / 128, B_SZ * N_HEADS), 512, 0, stream>>>(Qb, Kb, VTb, ctx);
  gemm_out<<<dim3(64, 8), 256, 0, stream>>>(
      ctx, w4 + 3 * (size_t)D_MODEL * D_MODEL, bo, out);
}

// Round 13
// 177.057 us; speedup vs baseline: 1.0383x; 1.0383x over previous
//
#include <hip/hip_runtime.h>
#include <hip/hip_bf16.h>
#include <math.h>

#define D_MODEL 512
#define N_HEADS 8
#define D_K     64
#define T_SEQ   2048
#define B_SZ    4
#define M_ROWS  (B_SZ * T_SEQ)   // 8192

typedef __bf16 bf16;
typedef __bf16 bf16x4 __attribute__((ext_vector_type(4)));
typedef __bf16 bf16x8 __attribute__((ext_vector_type(8)));
typedef float  floatx4 __attribute__((ext_vector_type(4)));

// 16B-atom XOR swizzle for stride-64 bf16 LDS tiles: conflict-free b128
// fragment access (padding cannot fix b128 tiles: stride%4dw==0 -> 8-way).
__device__ __forceinline__ int SWZ(int row, int col) {
  return row * 64 + ((((col >> 3) ^ (row & 7)) << 3) | (col & 7));
}

// ---------------------------------------------------------------------------
// Sinusoidal PE value for (t, d), d in [0,64) — fast intrinsics.
// ---------------------------------------------------------------------------
__device__ __forceinline__ float pe_fast(int t, int d) {
  int i2 = d & ~1;
  float div = __expf((float)i2 * (-0.1439115683f));  // -ln(10000)/64
  float ang = (float)t * div;
  return (d & 1) ? __cosf(ang) : __sinf(ang);
}

// ---------------------------------------------------------------------------
// prep v3: one-wave-per-row LayerNorm (blocks 0..2047, 4 rows/block) +
// weight f32->bf16 convert (blocks 2048..3071, one bf16x4 store).
// No LDS, no barriers.
// ---------------------------------------------------------------------------
__global__ __launch_bounds__(256) void prep(
    const float* __restrict__ x, const float* __restrict__ g,
    const float* __restrict__ b, bf16* __restrict__ out,
    const float* __restrict__ wq, const float* __restrict__ wk,
    const float* __restrict__ wv, const float* __restrict__ wo,
    bf16* __restrict__ wdst) {
  int bid = blockIdx.x;
  int tid = threadIdx.x;
  if (bid >= M_ROWS / 4) {
    int gid = (bid - M_ROWS / 4) * 256 + tid;
    int e0  = gid * 4;
    int mat = e0 >> 18;
    int loc = e0 & 262143;
    const float* src = (mat == 0) ? wq : (mat == 1) ? wk : (mat == 2) ? wv : wo;
    float4 v = *(const float4*)(src + loc);
    bf16x4 pk;
    pk[0] = (bf16)v.x; pk[1] = (bf16)v.y; pk[2] = (bf16)v.z; pk[3] = (bf16)v.w;
    *(bf16x4*)(wdst + e0) = pk;
    return;
  }
  int wave = tid >> 6, lane = tid & 63;
  int row  = bid * 4 + wave;
  const float* xr = x + (size_t)row * D_MODEL + lane * 8;
  float4 a = *(const float4*)(xr);
  float4 c = *(const float4*)(xr + 4);
  float s  = a.x + a.y + a.z + a.w + c.x + c.y + c.z + c.w;
  float ss = a.x * a.x + a.y * a.y + a.z * a.z + a.w * a.w +
             c.x * c.x + c.y * c.y + c.z * c.z + c.w * c.w;
#pragma unroll
  for (int off = 1; off < 64; off <<= 1) {
    s  += __shfl_xor(s,  off, 64);
    ss += __shfl_xor(ss, off, 64);
  }
  float mu  = s * (1.0f / D_MODEL);
  float var = ss * (1.0f / D_MODEL) - mu * mu;
  float rs  = rsqrtf(var + 1e-5f);
  float4 g0 = *(const float4*)(g + lane * 8);
  float4 g1 = *(const float4*)(g + lane * 8 + 4);
  float4 b0 = *(const float4*)(b + lane * 8);
  float4 b1 = *(const float4*)(b + lane * 8 + 4);
  bf16x8 o8;
  o8[0] = (bf16)((a.x - mu) * rs * g0.x + b0.x);
  o8[1] = (bf16)((a.y - mu) * rs * g0.y + b0.y);
  o8[2] = (bf16)((a.z - mu) * rs * g0.z + b0.z);
  o8[3] = (bf16)((a.w - mu) * rs * g0.w + b0.w);
  o8[4] = (bf16)((c.x - mu) * rs * g1.x + b1.x);
  o8[5] = (bf16)((c.y - mu) * rs * g1.y + b1.y);
  o8[6] = (bf16)((c.z - mu) * rs * g1.z + b1.z);
  o8[7] = (bf16)((c.w - mu) * rs * g1.w + b1.w);
  *(bf16x8*)(out + (size_t)row * D_MODEL + lane * 8) = o8;
}

// ---------------------------------------------------------------------------
// QKV projection v8 (reverted from v9) — K-SPLIT weights-resident LDS GEMM,
// af-loads AFTER the staging barrier. R12 post-mortem: issue-early af-loads
// cost ~5us net — the MFMA burst still waits on the staging barrier, so the
// hoist hid nothing and extended af's 32-VGPR live range across staging.
// This is the exact R10-measured config (total 178.98us).
// ---------------------------------------------------------------------------
__global__ __launch_bounds__(256, 3) void gemm_qkv(
    const bf16* __restrict__ A, const bf16* __restrict__ wqkv,
    const float* __restrict__ bq, const float* __restrict__ bk, const float* __restrict__ bv,
    bf16* __restrict__ Qo, bf16* __restrict__ Ko, bf16* __restrict__ VTo) {
  __shared__ bf16 sW[16384];             // 4 tiles of [64n][64k] = 32 KB
  __shared__ bf16 ep[4][1536];           // per-wave epilogue chunks (12 KB)

  int tid = threadIdx.x;
  int w = tid >> 6, lane = tid & 63;
  int lm = lane & 15, quad = lane >> 4;
  int mat  = blockIdx.y >> 3;            // 0=Q,1=K,2=V
  int h    = blockIdx.y & 7;
  int nloc = h * 64;
  const bf16* Wp = wqkv + (size_t)mat * 262144;

  int mbase = blockIdx.x * 128 + w * 32;
  const bf16* ap = A + (size_t)(mbase + lm) * D_MODEL + quad * 8;

  floatx4 acc[2][4];
#pragma unroll
  for (int mi = 0; mi < 2; mi++)
#pragma unroll
    for (int nt = 0; nt < 4; nt++) acc[mi][nt] = floatx4{0.f, 0.f, 0.f, 0.f};

  int srow = tid >> 2;
  int scc  = (tid & 3) * 16;

#pragma unroll 1
  for (int kp = 0; kp < 2; kp++) {
    if (kp) __syncthreads();             // all reads of phase-0 sW done
#pragma unroll
    for (int kc = 0; kc < 4; kc++) {
      const bf16* src = Wp + (size_t)(nloc + srow) * D_MODEL + kp * 256 + kc * 64 + scc;
      bf16x8 w0 = *(const bf16x8*)src;
      bf16x8 w1 = *(const bf16x8*)(src + 8);
      *(bf16x8*)&sW[kc * 4096 + SWZ(srow, scc)]     = w0;
      *(bf16x8*)&sW[kc * 4096 + SWZ(srow, scc + 8)] = w1;
    }
    __syncthreads();

    bf16x8 af[2][8];
#pragma unroll
    for (int mi = 0; mi < 2; mi++)
#pragma unroll
      for (int ks = 0; ks < 8; ks++)
        af[mi][ks] = *(const bf16x8*)(ap + mi * 16 * D_MODEL + kp * 256 + ks * 32);

#pragma unroll
    for (int ks = 0; ks < 8; ks++) {
#pragma unroll
      for (int nt = 0; nt < 4; nt++) {
        bf16x8 bfr = *(const bf16x8*)
            &sW[(ks >> 1) * 4096 + SWZ(nt * 16 + lm, (ks & 1) * 32 + quad * 8)];
        acc[0][nt] = __builtin_amdgcn_mfma_f32_16x16x32_bf16(af[0][ks], bfr, acc[0][nt], 0, 0, 0);
        acc[1][nt] = __builtin_amdgcn_mfma_f32_16x16x32_bf16(af[1][ks], bfr, acc[1][nt], 0, 0, 0);
      }
    }
  }

  // ---- epilogue (wave-private ep chunks) ----
  int bb = mbase >> 11, t0w = mbase & (T_SEQ - 1);
  size_t bhoff = (size_t)(bb * N_HEADS + h) * (T_SEQ * D_K);
  bf16* myep = ep[w];

  if (mat == 2) {
#pragma unroll
    for (int nt = 0; nt < 4; nt++) {
      float bvv = bv[nloc + nt * 16 + lm];
#pragma unroll
      for (int mi = 0; mi < 2; mi++) {
        bf16x4 pk;
#pragma unroll
        for (int rr = 0; rr < 4; rr++) pk[rr] = (bf16)(acc[mi][nt][rr] + bvv);
        *(bf16x4*)&myep[lm * 40 + mi * 16 + quad * 4] = pk;
      }
      int dl = lane >> 2, toff = (lane & 3) * 8;
      bf16x8 v = *(const bf16x8*)&myep[dl * 40 + toff];
      *(bf16x8*)(VTo + bhoff + (size_t)(nt * 16 + dl) * T_SEQ + t0w + toff) = v;
    }
  } else {
    bf16* dst = (mat == 0) ? Qo : Ko;
    const float* bias = (mat == 0) ? bq : bk;
#pragma unroll
    for (int c = 0; c < 2; c++) {
#pragma unroll
      for (int nt = 0; nt < 4; nt++) {
        int d = nt * 16 + lm;
        float bval = bias[nloc + d];
#pragma unroll
        for (int rr = 0; rr < 4; rr++) {
          float v = acc[c][nt][rr] + bval;
          if (mat == 1) v += pe_fast(t0w + c * 16 + quad * 4 + rr, d);
          else          v *= 0.125f;   // fold 1/sqrt(dk) into Q
          myep[(quad * 4 + rr) * 72 + d] = (bf16)v;
        }
      }
#pragma unroll
      for (int rd = 0; rd < 2; rd++) {
        int row = rd * 8 + (lane >> 3);
        bf16x8 v = *(const bf16x8*)&myep[row * 72 + (lane & 7) * 8];
        *(bf16x8*)(dst + bhoff + (size_t)(t0w + c * 16 + row) * D_K + (lane & 7) * 8) = v;
      }
    }
  }
}

// ---------------------------------------------------------------------------
// Output projection v5 (reverted from v6) — K-SPLIT, af-loads after the
// staging barrier. Exact R10-measured config.
// ---------------------------------------------------------------------------
__global__ __launch_bounds__(256, 3) void gemm_out(const bf16* __restrict__ A,
                                                   const bf16* __restrict__ W,
                                                   const float* __restrict__ bias,
                                                   float* __restrict__ out) {
  __shared__ bf16 sW[16384];             // 4 tiles of [64n][64k] = 32 KB
  int tid = threadIdx.x;
  int w = tid >> 6, lane = tid & 63;
  int lm = lane & 15, quad = lane >> 4;
  int n0 = blockIdx.y * 64;

  int mbase = blockIdx.x * 128 + w * 32;
  const bf16* ap = A + (size_t)(mbase + lm) * D_MODEL + quad * 8;

  floatx4 acc[2][4];
#pragma unroll
  for (int mi = 0; mi < 2; mi++)
#pragma unroll
    for (int nt = 0; nt < 4; nt++) acc[mi][nt] = floatx4{0.f, 0.f, 0.f, 0.f};

  int srow = tid >> 2;
  int scc  = (tid & 3) * 16;

#pragma unroll 1
  for (int kp = 0; kp < 2; kp++) {
    if (kp) __syncthreads();
#pragma unroll
    for (int kc = 0; kc < 4; kc++) {
      const bf16* src = W + (size_t)(n0 + srow) * D_MODEL + kp * 256 + kc * 64 + scc;
      bf16x8 w0 = *(const bf16x8*)src;
      bf16x8 w1 = *(const bf16x8*)(src + 8);
      *(bf16x8*)&sW[kc * 4096 + SWZ(srow, scc)]     = w0;
      *(bf16x8*)&sW[kc * 4096 + SWZ(srow, scc + 8)] = w1;
    }
    __syncthreads();

    bf16x8 af[2][8];
#pragma unroll
    for (int mi = 0; mi < 2; mi++)
#pragma unroll
      for (int ks = 0; ks < 8; ks++)
        af[mi][ks] = *(const bf16x8*)(ap + mi * 16 * D_MODEL + kp * 256 + ks * 32);

#pragma unroll
    for (int ks = 0; ks < 8; ks++) {
#pragma unroll
      for (int nt = 0; nt < 4; nt++) {
        bf16x8 bfr = *(const bf16x8*)
            &sW[(ks >> 1) * 4096 + SWZ(nt * 16 + lm, (ks & 1) * 32 + quad * 8)];
        acc[0][nt] = __builtin_amdgcn_mfma_f32_16x16x32_bf16(af[0][ks], bfr, acc[0][nt], 0, 0, 0);
        acc[1][nt] = __builtin_amdgcn_mfma_f32_16x16x32_bf16(af[1][ks], bfr, acc[1][nt], 0, 0, 0);
      }
    }
  }

#pragma unroll
  for (int nt = 0; nt < 4; nt++) {
    int n = n0 + nt * 16 + lm;
    float bval = bias[n];
#pragma unroll
    for (int mi = 0; mi < 2; mi++)
#pragma unroll
      for (int rr = 0; rr < 4; rr++) {
        int m = mbase + mi * 16 + quad * 4 + rr;
        out[(size_t)m * D_MODEL + n] = acc[mi][nt][rr] + bval;
      }
  }
}

// ---------------------------------------------------------------------------
// MFMA flash attention v11 — v6 (proven 58.2-59.2us) + deferred l_i
// reduction: the per-tile shfl_xor(16/32) pairs are linear in the sum, so
// accumulate raw per-lane partials across all 32 tiles and reduce ONCE
// before the merge (removes 128 cross-lane ops/wave from the hot loop;
// numerically identical up to fp reordering).
// ---------------------------------------------------------------------------
__global__ __launch_bounds__(512, 4) void flash_mfma(const bf16* __restrict__ Q,
                                                     const bf16* __restrict__ K,
                                                     const bf16* __restrict__ VT,
                                                     bf16* __restrict__ ctx) {
  __shared__ __align__(16) char smem[65536];
  bf16* sK  = (bf16*)smem;              // [2][64*64] 16 KB, swizzled
  bf16* sVT = (bf16*)(smem + 16384);    // [2][64*64] 16 KB, swizzled
  bf16* sP  = (bf16*)(smem + 32768);    // [8][32*64] 32 KB, swizzled

  int tid  = threadIdx.x;
  int wave = tid >> 6, lane = tid & 63;
  int lm = lane & 15, quad = lane >> 4;
  int qg = wave & 3, kg = wave >> 2;
  int bh = blockIdx.y;
  int q0 = blockIdx.x * 128 + qg * 32;

  const bf16* Qb  = Q  + (size_t)bh * T_SEQ * D_K;
  const bf16* Kb  = K  + (size_t)bh * T_SEQ * D_K;
  const bf16* VTb = VT + (size_t)bh * T_SEQ * D_K;  // [d][t]

  bf16x8 qf[2][2];
#pragma unroll
  for (int qt = 0; qt < 2; qt++)
#pragma unroll
    for (int kb = 0; kb < 2; kb++)
      qf[qt][kb] = *(const bf16x8*)(Qb + (size_t)(q0 + qt * 16 + lm) * D_K + kb * 32 + quad * 8);

  floatx4 o[2][4];
#pragma unroll
  for (int qt = 0; qt < 2; qt++)
#pragma unroll
    for (int nt = 0; nt < 4; nt++) o[qt][nt] = floatx4{0.f, 0.f, 0.f, 0.f};
  float l_i[2] = {0.f, 0.f};

  // staging: 512 threads x (1 b128 per tile per array); 2 tiles per round
  int srow = tid >> 3;
  int scol = (tid & 7) * 8;
  const bf16* kp0 = Kb  + (size_t)srow * D_K + scol;
  const bf16* vp0 = VTb + (size_t)srow * T_SEQ + scol;

  bf16x8 rk[2], rv[2];
  rk[0] = *(const bf16x8*)(kp0);
  rk[1] = *(const bf16x8*)(kp0 + 4096);
  rv[0] = *(const bf16x8*)(vp0);
  rv[1] = *(const bf16x8*)(vp0 + 64);

  bf16* myK = sK  + kg * 4096;
  bf16* myV = sVT + kg * 4096;
  bf16* myP = sP  + wave * 2048;

  for (int r = 0; r < T_SEQ / 64; r += 2) {
    __syncthreads();
    *(bf16x8*)&sK [SWZ(srow, scol)]         = rk[0];
    *(bf16x8*)&sK [4096 + SWZ(srow, scol)]  = rk[1];
    *(bf16x8*)&sVT[SWZ(srow, scol)]         = rv[0];
    *(bf16x8*)&sVT[4096 + SWZ(srow, scol)]  = rv[1];
    if (r + 2 < T_SEQ / 64) {
      rk[0] = *(const bf16x8*)(kp0 + (r + 2) * 4096);
      rk[1] = *(const bf16x8*)(kp0 + (r + 3) * 4096);
      rv[0] = *(const bf16x8*)(vp0 + (r + 2) * 64);
      rv[1] = *(const bf16x8*)(vp0 + (r + 3) * 64);
    }
    __syncthreads();

    // ---- this wave computes tile (r + kg): QK^T fused with softmax per nt ----
#pragma unroll
    for (int nt = 0; nt < 4; nt++) {
      floatx4 s0 = floatx4{0.f, 0.f, 0.f, 0.f};
      floatx4 s1 = floatx4{0.f, 0.f, 0.f, 0.f};
#pragma unroll
      for (int kb = 0; kb < 2; kb++) {
        bf16x8 kf = *(const bf16x8*)&myK[SWZ(nt * 16 + lm, kb * 32 + quad * 8)];
        s0 = __builtin_amdgcn_mfma_f32_16x16x32_bf16(kf, qf[0][kb], s0, 0, 0, 0);
        s1 = __builtin_amdgcn_mfma_f32_16x16x32_bf16(kf, qf[1][kb], s1, 0, 0, 0);
      }
      bf16x4 pk0, pk1;
#pragma unroll
      for (int rr = 0; rr < 4; rr++) {
        float p0 = __expf(s0[rr] - 8.0f);
        float p1 = __expf(s1[rr] - 8.0f);
        l_i[0] += p0; l_i[1] += p1;   // raw per-lane partials; reduced once after loop
        pk0[rr] = (bf16)p0; pk1[rr] = (bf16)p1;
      }
      *(bf16x4*)&myP[SWZ(lm,      nt * 16 + quad * 4)] = pk0;
      *(bf16x4*)&myP[SWZ(16 + lm, nt * 16 + quad * 4)] = pk1;
    }

#pragma unroll
    for (int kb = 0; kb < 2; kb++) {
      bf16x8 pf0 = *(const bf16x8*)&myP[SWZ(lm, kb * 32 + quad * 8)];
      bf16x8 pf1 = *(const bf16x8*)&myP[SWZ(16 + lm, kb * 32 + quad * 8)];
#pragma unroll
      for (int nt = 0; nt < 4; nt++) {
        bf16x8 vt = *(const bf16x8*)&myV[SWZ(nt * 16 + lm, kb * 32 + quad * 8)];
        o[0][nt] = __builtin_amdgcn_mfma_f32_16x16x32_bf16(pf0, vt, o[0][nt], 0, 0, 0);
        o[1][nt] = __builtin_amdgcn_mfma_f32_16x16x32_bf16(pf1, vt, o[1][nt], 0, 0, 0);
      }
    }
  }

  // ---- one-time l_i cross-quad reduction (was per-tile in v6) ----
#pragma unroll
  for (int qt = 0; qt < 2; qt++) {
    l_i[qt] += __shfl_xor(l_i[qt], 16, 64);
    l_i[qt] += __shfl_xor(l_i[qt], 32, 64);
  }

  // ---- merge the two k-group partials (once) ----
  __syncthreads();
  float* scO = (float*)smem;             // [4 qg][8][64 lanes] float4 = 32 KB
  float* scL = (float*)(smem + 32768);   // [4 qg][2][64] = 2 KB
  if (kg == 1) {
#pragma unroll
    for (int qt = 0; qt < 2; qt++)
#pragma unroll
      for (int nt = 0; nt < 4; nt++)
        *(floatx4*)&scO[(qg * 512 + (qt * 4 + nt) * 64 + lane) * 4] = o[qt][nt];
    scL[qg * 128 + lane]      = l_i[0];
    scL[qg * 128 + 64 + lane] = l_i[1];
  }
  __syncthreads();
  if (kg == 0) {
#pragma unroll
    for (int qt = 0; qt < 2; qt++)
#pragma unroll
      for (int nt = 0; nt < 4; nt++) {
        floatx4 t = *(const floatx4*)&scO[(qg * 512 + (qt * 4 + nt) * 64 + lane) * 4];
        o[qt][nt] += t;
      }
    l_i[0] += scL[qg * 128 + lane];
    l_i[1] += scL[qg * 128 + 64 + lane];

    int b_ = bh >> 3, h = bh & 7;
#pragma unroll
    for (int qt = 0; qt < 2; qt++) {
#pragma unroll
      for (int rr = 0; rr < 4; rr++) {
        int qq = quad * 4 + rr;
        float linv = 1.f / __shfl(l_i[qt], qq, 64);
        int t = q0 + qt * 16 + qq;
        bf16* op = ctx + ((size_t)(b_ * T_SEQ + t)) * D_MODEL + h * D_K;
#pragma unroll
        for (int nt = 0; nt < 4; nt++)
          op[nt * 16 + lm] = (bf16)(o[qt][nt][rr] * linv);
      }
    }
  }
}

// ---------------------------------------------------------------------------
extern "C" void kernel_launch(void* const* d_in, const int* in_sizes, int n_in,
                              void* d_out, int out_size, void* d_ws, size_t ws_size,
                              hipStream_t stream) {
  const float* x    = (const float*)d_in[0];
  const float* ln_g = (const float*)d_in[1];
  const float* ln_b = (const float*)d_in[2];
  const float* wq   = (const float*)d_in[3];
  const float* bq   = (const float*)d_in[4];
  const float* wk   = (const float*)d_in[5];
  const float* bk   = (const float*)d_in[6];
  const float* wv   = (const float*)d_in[7];
  const float* bv   = (const float*)d_in[8];
  const float* wo   = (const float*)d_in[9];
  const float* bo   = (const float*)d_in[10];
  float* out = (float*)d_out;

  char* ws = (char*)d_ws;
  const size_t MB8 = (size_t)M_ROWS * D_MODEL * sizeof(bf16);  // 8 MB
  bf16* normed = (bf16*)(ws);                    // dead after gemm_qkv
  bf16* Qb     = (bf16*)(ws + MB8);
  bf16* Kb     = (bf16*)(ws + 2 * MB8);
  bf16* VTb    = (bf16*)(ws + 3 * MB8);          // V^T: [bh][d][t]
  bf16* w4     = (bf16*)(ws + 4 * MB8);          // 2 MB: wq|wk|wv|wo bf16
  bf16* ctx    = normed;                         // alias; ws total 34 MB

  prep<<<M_ROWS / 4 + 1024, 256, 0, stream>>>(x, ln_g, ln_b, normed,
                                              wq, wk, wv, wo, w4);
  gemm_qkv<<<dim3(64, 24), 256, 0, stream>>>(
      normed, w4, bq, bk, bv, Qb, Kb, VTb);
  flash_mfma<<<dim3(T_SEQ / 128, B_SZ * N_HEADS), 512, 0, stream>>>(Qb, Kb, VTb, ctx);
  gemm_out<<<dim3(64, 8), 256, 0, stream>>>(
      ctx, w4 + 3 * (size_t)D_MODEL * D_MODEL, bo, out);
}